// Round 6
// baseline (217.707 us; speedup 1.0000x reference)
//
#include <hip/hip_runtime.h>
#include <math.h>

// MoE top-2 router. Round 6: LDS-free, barrier-free GEMM. Each wave owns a
// private 16-token x 64-expert tile over a 512-k slice (KS=4). x fragments
// load straight to VGPRs (dense 128B segments/row, L3-resident); W comes from
// ws pre-shuffled into MFMA-B-fragment order (lane-coalesced, L2-resident).
// Explicit 3-slot x prefetch + 2-slot W double-buffer in registers; compiler
// emits fine-grained per-register vmcnt waits. 16 waves/CU, modest in-flight
// depth (~500 lines/CU) to stay inside the vmem queue.
//
// x: [16384, 2048] fp32, W: [64, 2048] fp32.
// outputs (concat, fp32): mask [T,64], idx-as-float [T,2],
//                         router_probs [T,64], probs [T,64]

#define D_DIM 2048
#define E_DIM 64
#define KS 4               // K-split
#define KSTEPS 16          // (D_DIM/KS)/32 k-steps per wave

typedef __bf16 bf16x8 __attribute__((ext_vector_type(8)));
typedef unsigned short us8 __attribute__((ext_vector_type(8)));
typedef float f32x4 __attribute__((ext_vector_type(4)));

static __device__ __forceinline__ unsigned short f2bf(float f) {
    unsigned int u = __float_as_uint(f);
    u += 0x7fffu + ((u >> 16) & 1u);   // RNE
    return (unsigned short)(u >> 16);
}
static __device__ __forceinline__ float bf2f(unsigned short h) {
    return __uint_as_float(((unsigned int)h) << 16);
}
static __device__ __forceinline__ void split4(const float4 v, ushort4* h, ushort4* l) {
    h->x = f2bf(v.x); l->x = f2bf(v.x - bf2f(h->x));
    h->y = f2bf(v.y); l->y = f2bf(v.y - bf2f(h->y));
    h->z = f2bf(v.z); l->z = f2bf(v.z - bf2f(h->z));
    h->w = f2bf(v.w); l->w = f2bf(v.w - bf2f(h->w));
}

// ---- convert W -> MFMA-B-fragment order, bf16 hi/lo (verified in r5) ----
// WB layout (16B units): [sg=0..63][n=0..3][h=0..1][lane=0..63]
//   fragment for lane (l16,quad): B[e = n*16+l16][k = sg*32 + quad*8 .. +7]
__global__ __launch_bounds__(256, 1) void convert_w(
    const float* __restrict__ W, unsigned short* __restrict__ WB)
{
    int u = blockIdx.x * 256 + threadIdx.x;     // 32768 outputs of 16B
    int lane = u & 63;
    int r = u >> 6;
    int h = r & 1;  r >>= 1;
    int n = r & 3;  int sg = r >> 2;
    int E  = n * 16 + (lane & 15);
    int k0 = sg * 32 + (lane >> 4) * 8;
    const float4* src = (const float4*)(W + (size_t)E * D_DIM + k0);
    float4 a = src[0], b = src[1];
    ushort4 ha, la, hb, lb;
    split4(a, &ha, &la);
    split4(b, &hb, &lb);
    us8 out = h ? (us8){la.x, la.y, la.z, la.w, lb.x, lb.y, lb.z, lb.w}
                : (us8){ha.x, ha.y, ha.z, ha.w, hb.x, hb.y, hb.z, hb.w};
    *(us8*)(WB + (size_t)u * 8) = out;
}

// ---- GEMM: 4 independent waves/block, wave = 16 tokens x 64 e x 512 k ----
__global__ __launch_bounds__(256, 4) void gemm_part(
    const float* __restrict__ x, const unsigned short* __restrict__ WB,
    float* __restrict__ P, int T)
{
    const int tid  = threadIdx.x;
    const int lane = tid & 63;
    const int wv   = tid >> 6;
    const int quad = lane >> 4;
    const int l16  = lane & 15;

    const int ntb = T >> 6;                 // 64-token block tiles
    const int tb  = blockIdx.x % ntb;
    const int ksl = blockIdx.x / ntb;
    const int t0  = (tb << 6) + wv * 16;    // this wave's 16 tokens
    const int kb  = ksl * (D_DIM / KS);

    // x A-fragment pointer: lane (l16,quad) reads row t0+l16, k = kb+quad*8
    // (+ s*32 per k-step; dense 128B per row segment, verified in r2)
    const float* xr = x + (size_t)(t0 + l16) * D_DIM + kb + quad * 8;
    // W fragment pointer: + s*4096 shorts per k-step, + (n*2+h)*512
    const unsigned short* wb = WB + ((size_t)(ksl * KSTEPS) * 512 + lane) * 8;

    f32x4 acc[4];
    #pragma unroll
    for (int n = 0; n < 4; ++n) { f32x4 z = {0.f, 0.f, 0.f, 0.f}; acc[n] = z; }

    float4 xa[3], xb[3];
    bf16x8 Wf[2][4][2];

    // prologue: 2 k-steps of x, 1 k-step of W in flight
    xa[0] = *(const float4*)(xr);        xb[0] = *(const float4*)(xr + 4);
    xa[1] = *(const float4*)(xr + 32);   xb[1] = *(const float4*)(xr + 36);
    #pragma unroll
    for (int n = 0; n < 4; ++n)
        #pragma unroll
        for (int h = 0; h < 2; ++h)
            Wf[0][n][h] = *(const bf16x8*)(wb + (n * 2 + h) * 512);

    #pragma unroll
    for (int s = 0; s < KSTEPS; ++s) {
        // prefetch x for s+2
        if (s + 2 < KSTEPS) {
            xa[(s + 2) % 3] = *(const float4*)(xr + (s + 2) * 32);
            xb[(s + 2) % 3] = *(const float4*)(xr + (s + 2) * 32 + 4);
        }
        // prefetch W for s+1
        if (s + 1 < KSTEPS) {
            #pragma unroll
            for (int n = 0; n < 4; ++n)
                #pragma unroll
                for (int h = 0; h < 2; ++h)
                    Wf[(s + 1) & 1][n][h] =
                        *(const bf16x8*)(wb + (size_t)(s + 1) * 4096 + (n * 2 + h) * 512);
        }

        // split current x k-step into bf16 hi/lo A-fragments
        ushort4 h0, l0, h1, l1;
        split4(xa[s % 3], &h0, &l0);
        split4(xb[s % 3], &h1, &l1);
        union { us8 u; bf16x8 b; } ua, ul;
        ua.u = (us8){h0.x, h0.y, h0.z, h0.w, h1.x, h1.y, h1.z, h1.w};
        ul.u = (us8){l0.x, l0.y, l0.z, l0.w, l1.x, l1.y, l1.z, l1.w};

        #pragma unroll
        for (int n = 0; n < 4; ++n) {
            acc[n] = __builtin_amdgcn_mfma_f32_16x16x32_bf16(ua.b, Wf[s & 1][n][0], acc[n], 0, 0, 0);
            acc[n] = __builtin_amdgcn_mfma_f32_16x16x32_bf16(ul.b, Wf[s & 1][n][0], acc[n], 0, 0, 0);
            acc[n] = __builtin_amdgcn_mfma_f32_16x16x32_bf16(ua.b, Wf[s & 1][n][1], acc[n], 0, 0, 0);
        }
    }

    // ---- write partial logits: P[ksl][t][e] ----
    float* Pb = P + ((size_t)ksl * T + t0) * 64;
    #pragma unroll
    for (int n = 0; n < 4; ++n)
        #pragma unroll
        for (int r = 0; r < 4; ++r)
            Pb[(quad * 4 + r) * 64 + n * 16 + l16] = acc[n][r];
}

// ---- reduce partials + softmax + top-2 + outputs; wave per 4 tokens ----
__global__ __launch_bounds__(256, 4) void reduce_router(
    const float* __restrict__ P, int T,
    float* __restrict__ mask_out, float* __restrict__ idx_out,
    float* __restrict__ rp_out, float* __restrict__ probs_out)
{
    const int tid  = threadIdx.x;
    const int lane = tid & 63;
    const int wv   = tid >> 6;

    for (int i = 0; i < 4; ++i) {
        int t = blockIdx.x * 16 + wv * 4 + i;
        float v = 0.f;
        #pragma unroll
        for (int s = 0; s < KS; ++s)
            v += P[((size_t)s * T + t) * 64 + lane];

        // argmax, lower-index tie-break (matches jax.lax.top_k)
        float bv = v; int bi = lane;
        #pragma unroll
        for (int off = 1; off < 64; off <<= 1) {
            float ov = __shfl_xor(bv, off, 64);
            int   oi = __shfl_xor(bi, off, 64);
            bool take = (ov > bv) || (ov == bv && oi < bi);
            bv = take ? ov : bv;
            bi = take ? oi : bi;
        }
        float m = bv; int i1 = bi;

        float p = __expf(v - m);
        float s = p;
        #pragma unroll
        for (int off = 1; off < 64; off <<= 1) s += __shfl_xor(s, off, 64);
        float prob = p / s;

        float v2 = (lane == i1) ? -INFINITY : v;
        float bv2 = v2; int bi2 = lane;
        #pragma unroll
        for (int off = 1; off < 64; off <<= 1) {
            float ov = __shfl_xor(bv2, off, 64);
            int   oi = __shfl_xor(bi2, off, 64);
            bool take = (ov > bv2) || (ov == bv2 && oi < bi2);
            bv2 = take ? ov : bv2;
            bi2 = take ? oi : bi2;
        }
        int i2 = bi2;

        float pd = __shfl(prob, i1, 64) + __shfl(prob, i2, 64);
        bool top = (lane == i1) || (lane == i2);

        mask_out[(size_t)t * 64 + lane]  = top ? 1.f : 0.f;
        rp_out[(size_t)t * 64 + lane]    = top ? prob / pd : 0.f;
        probs_out[(size_t)t * 64 + lane] = prob;
        if (lane == 0) {
            idx_out[(size_t)t * 2]     = (float)i1;
            idx_out[(size_t)t * 2 + 1] = (float)i2;
        }
    }
}

extern "C" void kernel_launch(void* const* d_in, const int* in_sizes, int n_in,
                              void* d_out, int out_size, void* d_ws, size_t ws_size,
                              hipStream_t stream) {
    const float* x = (const float*)d_in[0];
    const float* W = (const float*)d_in[1];
    float* out = (float*)d_out;

    const int T  = in_sizes[0] / D_DIM;     // 16384 tokens
    const int WN = in_sizes[1];             // 131072 elements

    unsigned short* WB = (unsigned short*)d_ws;         // 512 KB fragment-order W
    float* P = (float*)(WB + (size_t)WN * 2);           // KS partial slices (16 MB)

    float* mask_out  = out;
    float* idx_out   = out + (size_t)T * E_DIM;
    float* rp_out    = idx_out + (size_t)T * 2;
    float* probs_out = rp_out + (size_t)T * E_DIM;

    convert_w<<<dim3((WN * 2) / 8 / 256), dim3(256), 0, stream>>>(W, WB);
    gemm_part<<<dim3((T / 64) * KS), dim3(256), 0, stream>>>(x, WB, P, T);
    reduce_router<<<dim3(T / 16), dim3(256), 0, stream>>>(
        P, T, mask_out, idx_out, rp_out, probs_out);
}

// Round 7
// 215.611 us; speedup vs baseline: 1.0097x; 1.0097x over previous
//
#include <hip/hip_runtime.h>
#include <math.h>

// MoE top-2 router. Round 7: single fused kernel. 512-thr blocks = 8 waves =
// 2 token-groups x 4 k-slices; each wave = r6's barrier-free inner loop
// (16 tokens x 64 experts x 512 k, x fragments direct to VGPR with 3-slot
// prefetch, W from ws in MFMA-B-fragment order, lane-coalesced); then ONE
// __syncthreads, LDS partial-reduce, in-block softmax/top2/epilogue.
// Eliminates the P partials round-trip (33.6 MB) and the reduce kernel.
//
// x: [16384, 2048] fp32, W: [64, 2048] fp32.
// outputs (concat, fp32): mask [T,64], idx-as-float [T,2],
//                         router_probs [T,64], probs [T,64]

#define D_DIM 2048
#define E_DIM 64
#define KS 4               // K-split (waves per token-group)
#define KSTEPS 16          // (D_DIM/KS)/32 k-steps per wave

typedef __bf16 bf16x8 __attribute__((ext_vector_type(8)));
typedef unsigned short us8 __attribute__((ext_vector_type(8)));
typedef float f32x4 __attribute__((ext_vector_type(4)));

static __device__ __forceinline__ unsigned short f2bf(float f) {
    unsigned int u = __float_as_uint(f);
    u += 0x7fffu + ((u >> 16) & 1u);   // RNE
    return (unsigned short)(u >> 16);
}
static __device__ __forceinline__ float bf2f(unsigned short h) {
    return __uint_as_float(((unsigned int)h) << 16);
}
static __device__ __forceinline__ void split4(const float4 v, ushort4* h, ushort4* l) {
    h->x = f2bf(v.x); l->x = f2bf(v.x - bf2f(h->x));
    h->y = f2bf(v.y); l->y = f2bf(v.y - bf2f(h->y));
    h->z = f2bf(v.z); l->z = f2bf(v.z - bf2f(h->z));
    h->w = f2bf(v.w); l->w = f2bf(v.w - bf2f(h->w));
}

// ---- convert W -> MFMA-B-fragment order, bf16 hi/lo (verified r5/r6) ----
// WB layout (16B units): [sg=0..63][n=0..3][h=0..1][lane=0..63]
//   fragment for lane (l16,quad): B[e = n*16+l16][k = sg*32 + quad*8 .. +7]
__global__ __launch_bounds__(256, 1) void convert_w(
    const float* __restrict__ W, unsigned short* __restrict__ WB)
{
    int u = blockIdx.x * 256 + threadIdx.x;     // 32768 outputs of 16B
    int lane = u & 63;
    int r = u >> 6;
    int h = r & 1;  r >>= 1;
    int n = r & 3;  int sg = r >> 2;
    int E  = n * 16 + (lane & 15);
    int k0 = sg * 32 + (lane >> 4) * 8;
    const float4* src = (const float4*)(W + (size_t)E * D_DIM + k0);
    float4 a = src[0], b = src[1];
    ushort4 ha, la, hb, lb;
    split4(a, &ha, &la);
    split4(b, &hb, &lb);
    us8 out = h ? (us8){la.x, la.y, la.z, la.w, lb.x, lb.y, lb.z, lb.w}
                : (us8){ha.x, ha.y, ha.z, ha.w, hb.x, hb.y, hb.z, hb.w};
    *(us8*)(WB + (size_t)u * 8) = out;
}

// ---- fused: GEMM (K-split across 4 waves) + reduce + softmax + top2 ----
__global__ __launch_bounds__(512, 4) void router_fused(
    const float* __restrict__ x, const unsigned short* __restrict__ WB,
    float* __restrict__ mask_out, float* __restrict__ idx_out,
    float* __restrict__ rp_out, float* __restrict__ probs_out)
{
    __shared__ __align__(16) float PART[8 * 64 * 16];   // 32 KB partials

    const int tid  = threadIdx.x;
    const int lane = tid & 63;
    const int wv   = tid >> 6;          // 0..7
    const int g    = wv >> 2;           // token group 0..1
    const int ksl  = wv & 3;            // k slice 0..3
    const int quad = lane >> 4;
    const int l16  = lane & 15;

    const int tb = blockIdx.x * 32;     // block's 32 tokens
    const int t0 = tb + g * 16;         // this wave's 16 tokens
    const int kb = ksl * (D_DIM / KS);

    // x A-fragment: lane (l16,quad) reads row t0+l16, k = kb+quad*8 (+s*32)
    const float* xr = x + (size_t)(t0 + l16) * D_DIM + kb + quad * 8;
    // W fragment: + s*4096 shorts per k-step, + (n*2+h)*512
    const unsigned short* wb = WB + ((size_t)(ksl * KSTEPS) * 512 + lane) * 8;

    f32x4 acc[4];
    #pragma unroll
    for (int n = 0; n < 4; ++n) { f32x4 z = {0.f, 0.f, 0.f, 0.f}; acc[n] = z; }

    float4 xa[3], xb[3];
    bf16x8 Wf[2][4][2];

    // prologue: 2 k-steps of x, 1 k-step of W in flight
    xa[0] = *(const float4*)(xr);        xb[0] = *(const float4*)(xr + 4);
    xa[1] = *(const float4*)(xr + 32);   xb[1] = *(const float4*)(xr + 36);
    #pragma unroll
    for (int n = 0; n < 4; ++n)
        #pragma unroll
        for (int h = 0; h < 2; ++h)
            Wf[0][n][h] = *(const bf16x8*)(wb + (n * 2 + h) * 512);

    #pragma unroll
    for (int s = 0; s < KSTEPS; ++s) {
        if (s + 2 < KSTEPS) {
            xa[(s + 2) % 3] = *(const float4*)(xr + (s + 2) * 32);
            xb[(s + 2) % 3] = *(const float4*)(xr + (s + 2) * 32 + 4);
        }
        if (s + 1 < KSTEPS) {
            #pragma unroll
            for (int n = 0; n < 4; ++n)
                #pragma unroll
                for (int h = 0; h < 2; ++h)
                    Wf[(s + 1) & 1][n][h] =
                        *(const bf16x8*)(wb + (size_t)(s + 1) * 4096 + (n * 2 + h) * 512);
        }

        ushort4 h0, l0, h1, l1;
        split4(xa[s % 3], &h0, &l0);
        split4(xb[s % 3], &h1, &l1);
        union { us8 u; bf16x8 b; } ua, ul;
        ua.u = (us8){h0.x, h0.y, h0.z, h0.w, h1.x, h1.y, h1.z, h1.w};
        ul.u = (us8){l0.x, l0.y, l0.z, l0.w, l1.x, l1.y, l1.z, l1.w};

        #pragma unroll
        for (int n = 0; n < 4; ++n) {
            acc[n] = __builtin_amdgcn_mfma_f32_16x16x32_bf16(ua.b, Wf[s & 1][n][0], acc[n], 0, 0, 0);
            acc[n] = __builtin_amdgcn_mfma_f32_16x16x32_bf16(ul.b, Wf[s & 1][n][0], acc[n], 0, 0, 0);
            acc[n] = __builtin_amdgcn_mfma_f32_16x16x32_bf16(ua.b, Wf[s & 1][n][1], acc[n], 0, 0, 0);
        }
    }

    // ---- partials to LDS, one barrier ----
    #pragma unroll
    for (int n = 0; n < 4; ++n)
        #pragma unroll
        for (int r = 0; r < 4; ++r)
            PART[(wv * 64 + lane) * 16 + n * 4 + r] = acc[n][r];
    __syncthreads();

    // ---- epilogue: wave wv handles block-local tokens wv*4..+3, lane = expert
    // C-layout source for (tt,e): wave g*4+s, lane (tt>>2)*16+(e&15),
    // reg (e>>4)*4 + (tt&3)    [m89/m91, verified r1..r6]
    for (int i = 0; i < 4; ++i) {
        const int t  = wv * 4 + i;              // 0..31 block-local
        const int gg = t >> 4, tt = t & 15;
        const int e  = lane;
        const int fo = ((tt >> 2) * 16 + (e & 15)) * 16 + (e >> 4) * 4 + (tt & 3);

        float v = PART[(gg * 4 + 0) * 1024 + fo]
                + PART[(gg * 4 + 1) * 1024 + fo]
                + PART[(gg * 4 + 2) * 1024 + fo]
                + PART[(gg * 4 + 3) * 1024 + fo];

        // argmax, lower-index tie-break (matches jax.lax.top_k)
        float bv = v; int bi = lane;
        #pragma unroll
        for (int off = 1; off < 64; off <<= 1) {
            float ov = __shfl_xor(bv, off, 64);
            int   oi = __shfl_xor(bi, off, 64);
            bool take = (ov > bv) || (ov == bv && oi < bi);
            bv = take ? ov : bv;
            bi = take ? oi : bi;
        }
        float m = bv; int i1 = bi;

        float p = __expf(v - m);
        float s = p;
        #pragma unroll
        for (int off = 1; off < 64; off <<= 1) s += __shfl_xor(s, off, 64);
        float prob = p / s;

        float v2 = (lane == i1) ? -INFINITY : v;
        float bv2 = v2; int bi2 = lane;
        #pragma unroll
        for (int off = 1; off < 64; off <<= 1) {
            float ov = __shfl_xor(bv2, off, 64);
            int   oi = __shfl_xor(bi2, off, 64);
            bool take = (ov > bv2) || (ov == bv2 && oi < bi2);
            bv2 = take ? ov : bv2;
            bi2 = take ? oi : bi2;
        }
        int i2 = bi2;

        float pd = __shfl(prob, i1, 64) + __shfl(prob, i2, 64);
        const size_t gt = (size_t)(tb + t);     // global token
        bool top = (lane == i1) || (lane == i2);

        mask_out[gt * 64 + lane]  = top ? 1.f : 0.f;
        rp_out[gt * 64 + lane]    = top ? prob / pd : 0.f;
        probs_out[gt * 64 + lane] = prob;
        if (lane == 0) {
            idx_out[gt * 2]     = (float)i1;
            idx_out[gt * 2 + 1] = (float)i2;
        }
    }
}

extern "C" void kernel_launch(void* const* d_in, const int* in_sizes, int n_in,
                              void* d_out, int out_size, void* d_ws, size_t ws_size,
                              hipStream_t stream) {
    const float* x = (const float*)d_in[0];
    const float* W = (const float*)d_in[1];
    float* out = (float*)d_out;

    const int T  = in_sizes[0] / D_DIM;     // 16384 tokens
    const int WN = in_sizes[1];             // 131072 elements

    unsigned short* WB = (unsigned short*)d_ws;   // 512 KB fragment-order W

    float* mask_out  = out;
    float* idx_out   = out + (size_t)T * E_DIM;
    float* rp_out    = idx_out + (size_t)T * 2;
    float* probs_out = rp_out + (size_t)T * E_DIM;

    convert_w<<<dim3((WN * 2) / 8 / 256), dim3(256), 0, stream>>>(W, WB);
    router_fused<<<dim3(T / 32), dim3(512), 0, stream>>>(
        x, WB, mask_out, idx_out, rp_out, probs_out);
}